// Round 3
// baseline (42.430 us; speedup 1.0000x reference)
//
#include <hip/hip_runtime.h>
#include <math.h>

#define BB 4
#define NN 256
#define FCH 512
#define GCH 256
#define HID 128
#define ROWS 1024
#define NBF (ROWS / 8)      // 128 f-blocks (8 rows each)

// ---------------- kernel 1: fused projection (f and g) + scf/scg pre-contract ----------------
// pf[row][h] = feat[row,:] @ Wf + bf   (natural layout, float4-friendly over h)
// block = 256 thr = 32 ch-groups(4ch) x 8 rows; full K per thread (no reduce phase)
__global__ __launch_bounds__(256) void proj_fg_kernel(
    const float* __restrict__ feat, const float* __restrict__ gfeat,
    const float* __restrict__ Wf, const float* __restrict__ bf,
    const float* __restrict__ Wg, const float* __restrict__ bg,
    const float* __restrict__ Cf, const float* __restrict__ Cg,
    const float* __restrict__ a_w,
    float* __restrict__ pf, float* __restrict__ pg, float* __restrict__ scfg)
{
    const int t = threadIdx.x;
    if (blockIdx.x == 2 * NBF) {
        // scf[h] = sum_k a_w[k]*Cf[k][h]; scg likewise (cst term cancels in softmax)
        if (t < HID) {
            float s = 0.f;
            for (int k = 0; k < HID; ++k) s = fmaf(a_w[k], Cf[k * HID + t], s);
            scfg[t] = s;
        } else {
            const int h = t - HID;
            float s = 0.f;
            for (int k = 0; k < HID; ++k) s = fmaf(a_w[k], Cg[k * HID + h], s);
            scfg[HID + h] = s;
        }
        return;
    }
    __shared__ __align__(16) float srow[8 * FCH];   // 16 KB max
    const bool isF = blockIdx.x < NBF;
    const int blk = isF ? blockIdx.x : blockIdx.x - NBF;
    const int in_ch = isF ? FCH : GCH;
    const float* __restrict__ in = isF ? feat : gfeat;
    const float* __restrict__ W = isF ? Wf : Wg;
    const float* __restrict__ bias = isF ? bf : bg;
    float* __restrict__ dst = isF ? pf : pg;
    const int r0 = blk * 8;

    const int tot = 8 * in_ch;
    for (int i = 4 * t; i < tot; i += 4 * 256)
        *(float4*)&srow[i] = *(const float4*)&in[(size_t)r0 * in_ch + i];
    __syncthreads();

    const int chg = (t & 31) * 4;
    const int row = t >> 5;
    const float* __restrict__ sr = &srow[row * in_ch];

    float ax = 0.f, ay = 0.f, az = 0.f, aw = 0.f;
    #pragma unroll 8
    for (int c = 0; c < in_ch; c += 4) {
        const float4 s  = *(const float4*)&sr[c];
        const float4 w0 = *(const float4*)&W[(size_t)(c + 0) * HID + chg];
        const float4 w1 = *(const float4*)&W[(size_t)(c + 1) * HID + chg];
        const float4 w2 = *(const float4*)&W[(size_t)(c + 2) * HID + chg];
        const float4 w3 = *(const float4*)&W[(size_t)(c + 3) * HID + chg];
        ax = fmaf(s.x, w0.x, ax); ay = fmaf(s.x, w0.y, ay); az = fmaf(s.x, w0.z, az); aw = fmaf(s.x, w0.w, aw);
        ax = fmaf(s.y, w1.x, ax); ay = fmaf(s.y, w1.y, ay); az = fmaf(s.y, w1.z, az); aw = fmaf(s.y, w1.w, aw);
        ax = fmaf(s.z, w2.x, ax); ay = fmaf(s.z, w2.y, ay); az = fmaf(s.z, w2.z, az); aw = fmaf(s.z, w2.w, aw);
        ax = fmaf(s.w, w3.x, ax); ay = fmaf(s.w, w3.y, ay); az = fmaf(s.w, w3.z, az); aw = fmaf(s.w, w3.w, aw);
    }
    const float4 bsv = *(const float4*)&bias[chg];
    float4 o;
    o.x = ax + bsv.x; o.y = ay + bsv.y; o.z = az + bsv.z; o.w = aw + bsv.w;
    *(float4*)&dst[(size_t)(r0 + row) * HID + chg] = o;
}

// ---------------- kernel 2: att + masked softmax, 4n x 4m register tile ----------------
// block = 512 thr = 64 m-groups(4m) x 8 h-slices(16h); grid = BB*64 (4 n-rows per block)
#define HS 8
#define USTR 36     // words per 16-h block: 8 distinct bank-groups for hs=0..7, 16B aligned
#define UELEMS (4 * HS * USTR)
#define UIDX(j, h) ((j) * (HS * USTR) + ((h) >> 4) * USTR + ((h) & 15))

__global__ __launch_bounds__(512, 2) void att_kernel(
    const float* __restrict__ pf, const float* __restrict__ pg,
    const float* __restrict__ adj, const float* __restrict__ scfg,
    float* __restrict__ out)
{
    __shared__ __align__(16) float ufc[UELEMS], uf2s[UELEMS], ugc[UELEMS], ug2s[UELEMS];
    __shared__ __align__(16) float att_s[4][NN];

    const int t = threadIdx.x;
    const int b = blockIdx.x >> 6;
    const int n0 = (blockIdx.x & 63) * 4;

    // stage u-row derived arrays (4 rows x 128 h), padded layout
    {
        const int j = t >> 7;
        const int h = t & (HID - 1);
        const float sf = scfg[h];
        const float sg = scfg[HID + h];
        const float uf = pf[(size_t)(b * NN + n0 + j) * HID + h];
        const float ug = pg[(size_t)(b * NN + n0 + j) * HID + h];
        const int ui = UIDX(j, h);
        ufc[ui] = uf * sf;
        uf2s[ui] = uf * uf;
        ugc[ui] = ug * sg;
        ug2s[ui] = ug * ug;
    }
    __syncthreads();

    const int hs = t & 7;
    const int mg = t >> 3;
    const int m0 = mg * 4;
    const int hbase = hs * 16;

    float numf[4][4] = {}, denf[4][4] = {}, numg[4][4] = {}, deng[4][4] = {};

    #pragma unroll
    for (int it = 0; it < 4; ++it) {
        const int h = hbase + it * 4;
        float4 vf[4], vg[4], wf[4], wg[4];
        #pragma unroll
        for (int k = 0; k < 4; ++k) {
            vf[k] = *(const float4*)&pf[(size_t)(b * NN + m0 + k) * HID + h];
            vg[k] = *(const float4*)&pg[(size_t)(b * NN + m0 + k) * HID + h];
            wf[k].x = vf[k].x * vf[k].x; wf[k].y = vf[k].y * vf[k].y;
            wf[k].z = vf[k].z * vf[k].z; wf[k].w = vf[k].w * vf[k].w;
            wg[k].x = vg[k].x * vg[k].x; wg[k].y = vg[k].y * vg[k].y;
            wg[k].z = vg[k].z * vg[k].z; wg[k].w = vg[k].w * vg[k].w;
        }
        #pragma unroll
        for (int j = 0; j < 4; ++j) {
            const int ui = j * (HS * USTR) + hs * USTR + it * 4;
            const float4 c = *(const float4*)&ufc[ui];
            const float4 q = *(const float4*)&uf2s[ui];
            const float4 d = *(const float4*)&ugc[ui];
            const float4 r = *(const float4*)&ug2s[ui];
            #pragma unroll
            for (int k = 0; k < 4; ++k) {
                numf[j][k] = fmaf(vf[k].x, c.x, numf[j][k]);
                numf[j][k] = fmaf(vf[k].y, c.y, numf[j][k]);
                numf[j][k] = fmaf(vf[k].z, c.z, numf[j][k]);
                numf[j][k] = fmaf(vf[k].w, c.w, numf[j][k]);
                denf[j][k] = fmaf(wf[k].x, q.x, denf[j][k]);
                denf[j][k] = fmaf(wf[k].y, q.y, denf[j][k]);
                denf[j][k] = fmaf(wf[k].z, q.z, denf[j][k]);
                denf[j][k] = fmaf(wf[k].w, q.w, denf[j][k]);
                numg[j][k] = fmaf(vg[k].x, d.x, numg[j][k]);
                numg[j][k] = fmaf(vg[k].y, d.y, numg[j][k]);
                numg[j][k] = fmaf(vg[k].z, d.z, numg[j][k]);
                numg[j][k] = fmaf(vg[k].w, d.w, numg[j][k]);
                deng[j][k] = fmaf(wg[k].x, r.x, deng[j][k]);
                deng[j][k] = fmaf(wg[k].y, r.y, deng[j][k]);
                deng[j][k] = fmaf(wg[k].z, r.z, deng[j][k]);
                deng[j][k] = fmaf(wg[k].w, r.w, deng[j][k]);
            }
        }
    }

    // reduce across the 8 h-slices (consecutive lanes) with width-8 butterflies
    #pragma unroll
    for (int j = 0; j < 4; ++j) {
        #pragma unroll
        for (int k = 0; k < 4; ++k) {
            #pragma unroll
            for (int off = 1; off < 8; off <<= 1) {
                numf[j][k] += __shfl_xor(numf[j][k], off, 8);
                denf[j][k] += __shfl_xor(denf[j][k], off, 8);
                numg[j][k] += __shfl_xor(numg[j][k], off, 8);
                deng[j][k] += __shfl_xor(deng[j][k], off, 8);
            }
        }
    }

    if (hs == 0) {
        #pragma unroll
        for (int j = 0; j < 4; ++j) {
            const float4 ad = *(const float4*)&adj[(size_t)(b * NN + n0 + j) * NN + m0];
            float4 a4;
            a4.x = numf[j][0] / fmaxf(sqrtf(denf[j][0]), 1e-12f) + numg[j][0] / fmaxf(sqrtf(deng[j][0]), 1e-12f);
            a4.y = numf[j][1] / fmaxf(sqrtf(denf[j][1]), 1e-12f) + numg[j][1] / fmaxf(sqrtf(deng[j][1]), 1e-12f);
            a4.z = numf[j][2] / fmaxf(sqrtf(denf[j][2]), 1e-12f) + numg[j][2] / fmaxf(sqrtf(deng[j][2]), 1e-12f);
            a4.w = numf[j][3] / fmaxf(sqrtf(denf[j][3]), 1e-12f) + numg[j][3] / fmaxf(sqrtf(deng[j][3]), 1e-12f);
            if (ad.x == 0.f) a4.x -= 1e22f;
            if (ad.y == 0.f) a4.y -= 1e22f;
            if (ad.z == 0.f) a4.z -= 1e22f;
            if (ad.w == 0.f) a4.w -= 1e22f;
            *(float4*)&att_s[j][m0] = a4;
        }
    }
    __syncthreads();

    // softmax: wave w (<4) handles row w; 64 lanes x 4 m each
    const int w = t >> 6;
    const int lane = t & 63;
    if (w < 4) {
        const float4 v = *(const float4*)&att_s[w][lane * 4];
        float mx = fmaxf(fmaxf(v.x, v.y), fmaxf(v.z, v.w));
        #pragma unroll
        for (int off = 1; off < 64; off <<= 1) mx = fmaxf(mx, __shfl_xor(mx, off, 64));
        float4 e;
        e.x = __expf(v.x - mx); e.y = __expf(v.y - mx);
        e.z = __expf(v.z - mx); e.w = __expf(v.w - mx);
        float s = e.x + e.y + e.z + e.w;
        #pragma unroll
        for (int off = 1; off < 64; off <<= 1) s += __shfl_xor(s, off, 64);
        const float inv = 1.f / s;
        float4 o;
        o.x = e.x * inv; o.y = e.y * inv; o.z = e.z * inv; o.w = e.w * inv;
        *(float4*)&out[(size_t)(b * NN + n0 + w) * NN + lane * 4] = o;
    }
}

extern "C" void kernel_launch(void* const* d_in, const int* in_sizes, int n_in,
                              void* d_out, int out_size, void* d_ws, size_t ws_size,
                              hipStream_t stream) {
    const float* feat  = (const float*)d_in[0];
    const float* gfeat = (const float*)d_in[1];
    const float* adj   = (const float*)d_in[2];
    const float* Wf    = (const float*)d_in[3];
    const float* bf    = (const float*)d_in[4];
    const float* Wg    = (const float*)d_in[5];
    const float* bg    = (const float*)d_in[6];
    const float* Cf    = (const float*)d_in[7];
    const float* Cg    = (const float*)d_in[9];
    const float* a_w   = (const float*)d_in[11];
    float* out = (float*)d_out;

    float* pf   = (float*)d_ws;                    // [ROWS][HID] 512 KB
    float* pg   = pf + (size_t)ROWS * HID;         // [ROWS][HID] 512 KB
    float* scfg = pg + (size_t)ROWS * HID;         // [2*HID]

    proj_fg_kernel<<<2 * NBF + 1, 256, 0, stream>>>(feat, gfeat, Wf, bf, Wg, bg,
                                                    Cf, Cg, a_w, pf, pg, scfg);
    att_kernel<<<BB * 64, 512, 0, stream>>>(pf, pg, adj, scfg, out);
}

// Round 4
// 40.308 us; speedup vs baseline: 1.0527x; 1.0527x over previous
//
#include <hip/hip_runtime.h>
#include <math.h>

#define BB 4
#define NN 256
#define FCH 512
#define GCH 256
#define HID 128
#define ROWS 1024
#define SSTR 544          // padded LDS row stride (+4 floats per 64) -> conflict-free kq reads
#define SP(c) ((c) + (((c) >> 6) << 2))

// ---------------- kernel 1: fused projection (f and g) + scf/scg pre-contract ----------------
// block = 512 thr = 64 h-pairs x 8 K-quarters; W read exactly once per block;
// K-split reduced with width-8 shfl (kq = lane&7). f: 8 rows/block, g: 16 rows/block.
template <int RPBX, int INCH>
__device__ __forceinline__ void proj_body(const float* __restrict__ in,
                                          const float* __restrict__ W,
                                          const float* __restrict__ bias,
                                          float* __restrict__ dst,
                                          int r0, int t, float* srow) {
    // stage RPBX x INCH input rows, padded
    #pragma unroll
    for (int i = t; i < (RPBX * INCH) / 4; i += 512) {
        const int idx = i * 4;
        const int r = idx / INCH;
        const int c = idx - r * INCH;
        *(float4*)&srow[r * SSTR + SP(c)] = *(const float4*)&in[(size_t)r0 * INCH + idx];
    }
    __syncthreads();

    const int ch2 = t >> 3;          // 0..63 -> h = 2*ch2
    const int h = ch2 * 2;
    const int kq = t & 7;
    constexpr int cpk = INCH / 8;
    const int c0 = kq * cpk;

    float acc[RPBX][2];
    #pragma unroll
    for (int r = 0; r < RPBX; ++r) { acc[r][0] = 0.f; acc[r][1] = 0.f; }

    #pragma unroll 4
    for (int cc = 0; cc < cpk; cc += 4) {
        const int c = c0 + cc;
        const float2 w0 = *(const float2*)&W[(size_t)(c + 0) * HID + h];
        const float2 w1 = *(const float2*)&W[(size_t)(c + 1) * HID + h];
        const float2 w2 = *(const float2*)&W[(size_t)(c + 2) * HID + h];
        const float2 w3 = *(const float2*)&W[(size_t)(c + 3) * HID + h];
        #pragma unroll
        for (int r = 0; r < RPBX; ++r) {
            const float4 s = *(const float4*)&srow[r * SSTR + SP(c)];
            acc[r][0] = fmaf(s.x, w0.x, acc[r][0]); acc[r][1] = fmaf(s.x, w0.y, acc[r][1]);
            acc[r][0] = fmaf(s.y, w1.x, acc[r][0]); acc[r][1] = fmaf(s.y, w1.y, acc[r][1]);
            acc[r][0] = fmaf(s.z, w2.x, acc[r][0]); acc[r][1] = fmaf(s.z, w2.y, acc[r][1]);
            acc[r][0] = fmaf(s.w, w3.x, acc[r][0]); acc[r][1] = fmaf(s.w, w3.y, acc[r][1]);
        }
    }

    // reduce the 8 K-quarters (consecutive lanes) in-register
    #pragma unroll
    for (int r = 0; r < RPBX; ++r) {
        float a0 = acc[r][0], a1 = acc[r][1];
        #pragma unroll
        for (int off = 1; off < 8; off <<= 1) {
            a0 += __shfl_xor(a0, off, 8);
            a1 += __shfl_xor(a1, off, 8);
        }
        acc[r][0] = a0; acc[r][1] = a1;
    }
    if (kq == 0) {
        const float2 bs = *(const float2*)&bias[h];
        #pragma unroll
        for (int r = 0; r < RPBX; ++r) {
            float2 o; o.x = acc[r][0] + bs.x; o.y = acc[r][1] + bs.y;
            *(float2*)&dst[(size_t)(r0 + r) * HID + h] = o;
        }
    }
}

__global__ __launch_bounds__(512) void proj_fg_kernel(
    const float* __restrict__ feat, const float* __restrict__ gfeat,
    const float* __restrict__ Wf, const float* __restrict__ bf,
    const float* __restrict__ Wg, const float* __restrict__ bg,
    const float* __restrict__ Cf, const float* __restrict__ Cg,
    const float* __restrict__ a_w,
    float* __restrict__ pf, float* __restrict__ pg, float* __restrict__ scfg)
{
    __shared__ __align__(16) float srow[16 * SSTR];   // 34.8 KB
    const int t = threadIdx.x;
    const int bx = blockIdx.x;
    if (bx == 192) {
        // scf[h] = sum_k a_w[k]*Cf[k][h]; scg likewise (cst term cancels in softmax)
        if (t < HID) {
            float s = 0.f;
            for (int k = 0; k < HID; ++k) s = fmaf(a_w[k], Cf[k * HID + t], s);
            scfg[t] = s;
        } else if (t < 2 * HID) {
            const int hh = t - HID;
            float s = 0.f;
            for (int k = 0; k < HID; ++k) s = fmaf(a_w[k], Cg[k * HID + hh], s);
            scfg[HID + hh] = s;
        }
        return;
    }
    if (bx < 128) proj_body<8, FCH>(feat, Wf, bf, pf, bx * 8, t, srow);
    else          proj_body<16, GCH>(gfeat, Wg, bg, pg, (bx - 128) * 16, t, srow);
}

// ---------------- kernel 2: att + masked softmax, 4n x 4m register tile ----------------
// block = 512 thr = 64 m-groups(4m) x 8 h-slices(16h); grid = BB*64 (4 n-rows per block)
#define HS 8
#define USTR 36
#define UELEMS (4 * HS * USTR)
#define UIDX(j, h) ((j) * (HS * USTR) + ((h) >> 4) * USTR + ((h) & 15))

__global__ __launch_bounds__(512, 2) void att_kernel(
    const float* __restrict__ pf, const float* __restrict__ pg,
    const float* __restrict__ adj, const float* __restrict__ scfg,
    float* __restrict__ out)
{
    __shared__ __align__(16) float ufc[UELEMS], uf2s[UELEMS], ugc[UELEMS], ug2s[UELEMS];
    __shared__ __align__(16) float att_s[4][NN];

    const int t = threadIdx.x;
    const int b = blockIdx.x >> 6;
    const int n0 = (blockIdx.x & 63) * 4;

    {
        const int j = t >> 7;
        const int h = t & (HID - 1);
        const float sf = scfg[h];
        const float sg = scfg[HID + h];
        const float uf = pf[(size_t)(b * NN + n0 + j) * HID + h];
        const float ug = pg[(size_t)(b * NN + n0 + j) * HID + h];
        const int ui = UIDX(j, h);
        ufc[ui] = uf * sf;
        uf2s[ui] = uf * uf;
        ugc[ui] = ug * sg;
        ug2s[ui] = ug * ug;
    }
    __syncthreads();

    const int hs = t & 7;
    const int mg = t >> 3;
    const int m0 = mg * 4;
    const int hbase = hs * 16;

    float numf[4][4] = {}, denf[4][4] = {}, numg[4][4] = {}, deng[4][4] = {};

    #pragma unroll
    for (int it = 0; it < 4; ++it) {
        const int h = hbase + it * 4;
        float4 vf[4], vg[4], wf[4], wg[4];
        #pragma unroll
        for (int k = 0; k < 4; ++k) {
            vf[k] = *(const float4*)&pf[(size_t)(b * NN + m0 + k) * HID + h];
            vg[k] = *(const float4*)&pg[(size_t)(b * NN + m0 + k) * HID + h];
            wf[k].x = vf[k].x * vf[k].x; wf[k].y = vf[k].y * vf[k].y;
            wf[k].z = vf[k].z * vf[k].z; wf[k].w = vf[k].w * vf[k].w;
            wg[k].x = vg[k].x * vg[k].x; wg[k].y = vg[k].y * vg[k].y;
            wg[k].z = vg[k].z * vg[k].z; wg[k].w = vg[k].w * vg[k].w;
        }
        #pragma unroll
        for (int j = 0; j < 4; ++j) {
            const int ui = j * (HS * USTR) + hs * USTR + it * 4;
            const float4 c = *(const float4*)&ufc[ui];
            const float4 q = *(const float4*)&uf2s[ui];
            const float4 d = *(const float4*)&ugc[ui];
            const float4 r = *(const float4*)&ug2s[ui];
            #pragma unroll
            for (int k = 0; k < 4; ++k) {
                numf[j][k] = fmaf(vf[k].x, c.x, numf[j][k]);
                numf[j][k] = fmaf(vf[k].y, c.y, numf[j][k]);
                numf[j][k] = fmaf(vf[k].z, c.z, numf[j][k]);
                numf[j][k] = fmaf(vf[k].w, c.w, numf[j][k]);
                denf[j][k] = fmaf(wf[k].x, q.x, denf[j][k]);
                denf[j][k] = fmaf(wf[k].y, q.y, denf[j][k]);
                denf[j][k] = fmaf(wf[k].z, q.z, denf[j][k]);
                denf[j][k] = fmaf(wf[k].w, q.w, denf[j][k]);
                numg[j][k] = fmaf(vg[k].x, d.x, numg[j][k]);
                numg[j][k] = fmaf(vg[k].y, d.y, numg[j][k]);
                numg[j][k] = fmaf(vg[k].z, d.z, numg[j][k]);
                numg[j][k] = fmaf(vg[k].w, d.w, numg[j][k]);
                deng[j][k] = fmaf(wg[k].x, r.x, deng[j][k]);
                deng[j][k] = fmaf(wg[k].y, r.y, deng[j][k]);
                deng[j][k] = fmaf(wg[k].z, r.z, deng[j][k]);
                deng[j][k] = fmaf(wg[k].w, r.w, deng[j][k]);
            }
        }
    }

    #pragma unroll
    for (int j = 0; j < 4; ++j) {
        #pragma unroll
        for (int k = 0; k < 4; ++k) {
            #pragma unroll
            for (int off = 1; off < 8; off <<= 1) {
                numf[j][k] += __shfl_xor(numf[j][k], off, 8);
                denf[j][k] += __shfl_xor(denf[j][k], off, 8);
                numg[j][k] += __shfl_xor(numg[j][k], off, 8);
                deng[j][k] += __shfl_xor(deng[j][k], off, 8);
            }
        }
    }

    if (hs == 0) {
        #pragma unroll
        for (int j = 0; j < 4; ++j) {
            const float4 ad = *(const float4*)&adj[(size_t)(b * NN + n0 + j) * NN + m0];
            float4 a4;
            a4.x = numf[j][0] / fmaxf(sqrtf(denf[j][0]), 1e-12f) + numg[j][0] / fmaxf(sqrtf(deng[j][0]), 1e-12f);
            a4.y = numf[j][1] / fmaxf(sqrtf(denf[j][1]), 1e-12f) + numg[j][1] / fmaxf(sqrtf(deng[j][1]), 1e-12f);
            a4.z = numf[j][2] / fmaxf(sqrtf(denf[j][2]), 1e-12f) + numg[j][2] / fmaxf(sqrtf(deng[j][2]), 1e-12f);
            a4.w = numf[j][3] / fmaxf(sqrtf(denf[j][3]), 1e-12f) + numg[j][3] / fmaxf(sqrtf(deng[j][3]), 1e-12f);
            if (ad.x == 0.f) a4.x -= 1e22f;
            if (ad.y == 0.f) a4.y -= 1e22f;
            if (ad.z == 0.f) a4.z -= 1e22f;
            if (ad.w == 0.f) a4.w -= 1e22f;
            *(float4*)&att_s[j][m0] = a4;
        }
    }
    __syncthreads();

    const int w = t >> 6;
    const int lane = t & 63;
    if (w < 4) {
        const float4 v = *(const float4*)&att_s[w][lane * 4];
        float mx = fmaxf(fmaxf(v.x, v.y), fmaxf(v.z, v.w));
        #pragma unroll
        for (int off = 1; off < 64; off <<= 1) mx = fmaxf(mx, __shfl_xor(mx, off, 64));
        float4 e;
        e.x = __expf(v.x - mx); e.y = __expf(v.y - mx);
        e.z = __expf(v.z - mx); e.w = __expf(v.w - mx);
        float s = e.x + e.y + e.z + e.w;
        #pragma unroll
        for (int off = 1; off < 64; off <<= 1) s += __shfl_xor(s, off, 64);
        const float inv = 1.f / s;
        float4 o;
        o.x = e.x * inv; o.y = e.y * inv; o.z = e.z * inv; o.w = e.w * inv;
        *(float4*)&out[(size_t)(b * NN + n0 + w) * NN + lane * 4] = o;
    }
}

extern "C" void kernel_launch(void* const* d_in, const int* in_sizes, int n_in,
                              void* d_out, int out_size, void* d_ws, size_t ws_size,
                              hipStream_t stream) {
    const float* feat  = (const float*)d_in[0];
    const float* gfeat = (const float*)d_in[1];
    const float* adj   = (const float*)d_in[2];
    const float* Wf    = (const float*)d_in[3];
    const float* bf    = (const float*)d_in[4];
    const float* Wg    = (const float*)d_in[5];
    const float* bg    = (const float*)d_in[6];
    const float* Cf    = (const float*)d_in[7];
    const float* Cg    = (const float*)d_in[9];
    const float* a_w   = (const float*)d_in[11];
    float* out = (float*)d_out;

    float* pf   = (float*)d_ws;                    // [ROWS][HID] 512 KB
    float* pg   = pf + (size_t)ROWS * HID;         // [ROWS][HID] 512 KB
    float* scfg = pg + (size_t)ROWS * HID;         // [2*HID]

    proj_fg_kernel<<<193, 512, 0, stream>>>(feat, gfeat, Wf, bf, Wg, bg,
                                            Cf, Cg, a_w, pf, pg, scfg);
    att_kernel<<<BB * 64, 512, 0, stream>>>(pf, pg, adj, scfg, out);
}

// Round 5
// 29.720 us; speedup vs baseline: 1.4277x; 1.3562x over previous
//
#include <hip/hip_runtime.h>
#include <math.h>

#define BB 4
#define NN 256
#define FCH 512
#define GCH 256
#define HID 128
#define ROWS 1024

// ---------------- kernel 1: fused projection (f and g) + scf/scg ----------------
// 513 blocks x 256 thr. Block 0: scfg. Blocks 1..256: f. Blocks 257..512: g.
// Compute block tile: 8 rows x 64 h (h-half), K-split 8 via kq = t>>5.
// Wave W-load = 2 contiguous 256B segments; each W float2 feeds 16 fma (8 rows).
// Reduce: shfl_xor(32) pairs kq within wave, then 8KB LDS partial over 4 waves.
template <int INCH>
__device__ __forceinline__ void proj_body(const float* __restrict__ in,
                                          const float* __restrict__ W,
                                          const float* __restrict__ bias,
                                          float* __restrict__ dst,
                                          int r0, int hh, int t,
                                          float* __restrict__ srow,
                                          float* __restrict__ partial) {
    // stage 8 x INCH input rows, coalesced float4
    #pragma unroll
    for (int i = 4 * t; i < 8 * INCH; i += 4 * 256)
        *(float4*)&srow[i] = *(const float4*)&in[(size_t)r0 * INCH + i];
    __syncthreads();

    const int kq = t >> 5;                 // 0..7
    const int hp = t & 31;                 // 0..31
    const int h = hh + hp * 2;
    constexpr int cpk = INCH / 8;          // f:64 g:32
    const int c0 = kq * cpk;

    float acc[8][2];
    #pragma unroll
    for (int r = 0; r < 8; ++r) { acc[r][0] = 0.f; acc[r][1] = 0.f; }

    #pragma unroll 4
    for (int cc = 0; cc < cpk; cc += 4) {
        const int c = c0 + cc;
        const float2 w0 = *(const float2*)&W[(size_t)(c + 0) * HID + h];
        const float2 w1 = *(const float2*)&W[(size_t)(c + 1) * HID + h];
        const float2 w2 = *(const float2*)&W[(size_t)(c + 2) * HID + h];
        const float2 w3 = *(const float2*)&W[(size_t)(c + 3) * HID + h];
        #pragma unroll
        for (int r = 0; r < 8; ++r) {
            const float4 s = *(const float4*)&srow[r * INCH + c];   // wave-broadcast
            acc[r][0] = fmaf(s.x, w0.x, acc[r][0]); acc[r][1] = fmaf(s.x, w0.y, acc[r][1]);
            acc[r][0] = fmaf(s.y, w1.x, acc[r][0]); acc[r][1] = fmaf(s.y, w1.y, acc[r][1]);
            acc[r][0] = fmaf(s.z, w2.x, acc[r][0]); acc[r][1] = fmaf(s.z, w2.y, acc[r][1]);
            acc[r][0] = fmaf(s.w, w3.x, acc[r][0]); acc[r][1] = fmaf(s.w, w3.y, acc[r][1]);
        }
    }

    // pair-combine kq within wave (lane l <-> l^32 hold kq, kq^1 for same hp)
    #pragma unroll
    for (int r = 0; r < 8; ++r) {
        acc[r][0] += __shfl_xor(acc[r][0], 32, 64);
        acc[r][1] += __shfl_xor(acc[r][1], 32, 64);
    }
    const int w = t >> 6;                  // wave id 0..3 = kq-pair group
    if ((t & 63) < 32) {
        #pragma unroll
        for (int r = 0; r < 8; ++r)
            *(float2*)&partial[(((w * 8 + r) * 32) + hp) * 2] = *(float2*)&acc[r][0];
    }
    __syncthreads();

    // tail: thread (r = t>>5, hp = t&31) sums 4 partials + bias
    {
        const int r = t >> 5;
        const int hp2 = t & 31;
        const int h2 = hh + hp2 * 2;
        float2 s = *(const float2*)&bias[h2];
        #pragma unroll
        for (int ww = 0; ww < 4; ++ww) {
            const float2 p = *(const float2*)&partial[(((ww * 8 + r) * 32) + hp2) * 2];
            s.x += p.x; s.y += p.y;
        }
        *(float2*)&dst[(size_t)(r0 + r) * HID + h2] = s;
    }
}

__global__ __launch_bounds__(256) void proj_fg_kernel(
    const float* __restrict__ feat, const float* __restrict__ gfeat,
    const float* __restrict__ Wf, const float* __restrict__ bf,
    const float* __restrict__ Wg, const float* __restrict__ bg,
    const float* __restrict__ Cf, const float* __restrict__ Cg,
    const float* __restrict__ a_w,
    float* __restrict__ pf, float* __restrict__ pg, float* __restrict__ scfg)
{
    __shared__ __align__(16) float srow[8 * FCH];        // 16 KB
    __shared__ __align__(16) float partial[4 * 8 * 32 * 2]; // 8 KB
    const int t = threadIdx.x;
    const int bx = blockIdx.x;
    if (bx == 0) {
        // scf[h] = sum_k a_w[k]*Cf[k][h]; scg likewise (cst cancels in softmax)
        const float* C = (t < HID) ? Cf : Cg;
        const int h = t & (HID - 1);
        float a0 = 0.f, a1 = 0.f, a2 = 0.f, a3 = 0.f;
        #pragma unroll 4
        for (int k = 0; k < HID; k += 4) {
            a0 = fmaf(a_w[k + 0], C[(k + 0) * HID + h], a0);
            a1 = fmaf(a_w[k + 1], C[(k + 1) * HID + h], a1);
            a2 = fmaf(a_w[k + 2], C[(k + 2) * HID + h], a2);
            a3 = fmaf(a_w[k + 3], C[(k + 3) * HID + h], a3);
        }
        scfg[t] = (a0 + a1) + (a2 + a3);
        return;
    }
    if (bx <= 256) {
        const int blk = bx - 1;
        proj_body<FCH>(feat, Wf, bf, pf, (blk >> 1) * 8, (blk & 1) * 64, t, srow, partial);
    } else {
        const int blk = bx - 257;
        proj_body<GCH>(gfeat, Wg, bg, pg, (blk >> 1) * 8, (blk & 1) * 64, t, srow, partial);
    }
}

// ---------------- kernel 2: att + masked softmax, 4n x 4m register tile ----------------
#define HS 8
#define USTR 36
#define UELEMS (4 * HS * USTR)
#define UIDX(j, h) ((j) * (HS * USTR) + ((h) >> 4) * USTR + ((h) & 15))

__global__ __launch_bounds__(512, 2) void att_kernel(
    const float* __restrict__ pf, const float* __restrict__ pg,
    const float* __restrict__ adj, const float* __restrict__ scfg,
    float* __restrict__ out)
{
    __shared__ __align__(16) float ufc[UELEMS], uf2s[UELEMS], ugc[UELEMS], ug2s[UELEMS];
    __shared__ __align__(16) float att_s[4][NN];

    const int t = threadIdx.x;
    const int b = blockIdx.x >> 6;
    const int n0 = (blockIdx.x & 63) * 4;

    {
        const int j = t >> 7;
        const int h = t & (HID - 1);
        const float sf = scfg[h];
        const float sg = scfg[HID + h];
        const float uf = pf[(size_t)(b * NN + n0 + j) * HID + h];
        const float ug = pg[(size_t)(b * NN + n0 + j) * HID + h];
        const int ui = UIDX(j, h);
        ufc[ui] = uf * sf;
        uf2s[ui] = uf * uf;
        ugc[ui] = ug * sg;
        ug2s[ui] = ug * ug;
    }
    __syncthreads();

    const int hs = t & 7;
    const int mg = t >> 3;
    const int m0 = mg * 4;
    const int hbase = hs * 16;

    float numf[4][4] = {}, denf[4][4] = {}, numg[4][4] = {}, deng[4][4] = {};

    #pragma unroll
    for (int it = 0; it < 4; ++it) {
        const int h = hbase + it * 4;
        float4 vf[4], vg[4], wf[4], wg[4];
        #pragma unroll
        for (int k = 0; k < 4; ++k) {
            vf[k] = *(const float4*)&pf[(size_t)(b * NN + m0 + k) * HID + h];
            vg[k] = *(const float4*)&pg[(size_t)(b * NN + m0 + k) * HID + h];
            wf[k].x = vf[k].x * vf[k].x; wf[k].y = vf[k].y * vf[k].y;
            wf[k].z = vf[k].z * vf[k].z; wf[k].w = vf[k].w * vf[k].w;
            wg[k].x = vg[k].x * vg[k].x; wg[k].y = vg[k].y * vg[k].y;
            wg[k].z = vg[k].z * vg[k].z; wg[k].w = vg[k].w * vg[k].w;
        }
        #pragma unroll
        for (int j = 0; j < 4; ++j) {
            const int ui = j * (HS * USTR) + hs * USTR + it * 4;
            const float4 c = *(const float4*)&ufc[ui];
            const float4 q = *(const float4*)&uf2s[ui];
            const float4 d = *(const float4*)&ugc[ui];
            const float4 r = *(const float4*)&ug2s[ui];
            #pragma unroll
            for (int k = 0; k < 4; ++k) {
                numf[j][k] = fmaf(vf[k].x, c.x, numf[j][k]);
                numf[j][k] = fmaf(vf[k].y, c.y, numf[j][k]);
                numf[j][k] = fmaf(vf[k].z, c.z, numf[j][k]);
                numf[j][k] = fmaf(vf[k].w, c.w, numf[j][k]);
                denf[j][k] = fmaf(wf[k].x, q.x, denf[j][k]);
                denf[j][k] = fmaf(wf[k].y, q.y, denf[j][k]);
                denf[j][k] = fmaf(wf[k].z, q.z, denf[j][k]);
                denf[j][k] = fmaf(wf[k].w, q.w, denf[j][k]);
                numg[j][k] = fmaf(vg[k].x, d.x, numg[j][k]);
                numg[j][k] = fmaf(vg[k].y, d.y, numg[j][k]);
                numg[j][k] = fmaf(vg[k].z, d.z, numg[j][k]);
                numg[j][k] = fmaf(vg[k].w, d.w, numg[j][k]);
                deng[j][k] = fmaf(wg[k].x, r.x, deng[j][k]);
                deng[j][k] = fmaf(wg[k].y, r.y, deng[j][k]);
                deng[j][k] = fmaf(wg[k].z, r.z, deng[j][k]);
                deng[j][k] = fmaf(wg[k].w, r.w, deng[j][k]);
            }
        }
    }

    #pragma unroll
    for (int j = 0; j < 4; ++j) {
        #pragma unroll
        for (int k = 0; k < 4; ++k) {
            #pragma unroll
            for (int off = 1; off < 8; off <<= 1) {
                numf[j][k] += __shfl_xor(numf[j][k], off, 8);
                denf[j][k] += __shfl_xor(denf[j][k], off, 8);
                numg[j][k] += __shfl_xor(numg[j][k], off, 8);
                deng[j][k] += __shfl_xor(deng[j][k], off, 8);
            }
        }
    }

    if (hs == 0) {
        #pragma unroll
        for (int j = 0; j < 4; ++j) {
            const float4 ad = *(const float4*)&adj[(size_t)(b * NN + n0 + j) * NN + m0];
            float4 a4;
            a4.x = numf[j][0] / fmaxf(sqrtf(denf[j][0]), 1e-12f) + numg[j][0] / fmaxf(sqrtf(deng[j][0]), 1e-12f);
            a4.y = numf[j][1] / fmaxf(sqrtf(denf[j][1]), 1e-12f) + numg[j][1] / fmaxf(sqrtf(deng[j][1]), 1e-12f);
            a4.z = numf[j][2] / fmaxf(sqrtf(denf[j][2]), 1e-12f) + numg[j][2] / fmaxf(sqrtf(deng[j][2]), 1e-12f);
            a4.w = numf[j][3] / fmaxf(sqrtf(denf[j][3]), 1e-12f) + numg[j][3] / fmaxf(sqrtf(deng[j][3]), 1e-12f);
            if (ad.x == 0.f) a4.x -= 1e22f;
            if (ad.y == 0.f) a4.y -= 1e22f;
            if (ad.z == 0.f) a4.z -= 1e22f;
            if (ad.w == 0.f) a4.w -= 1e22f;
            *(float4*)&att_s[j][m0] = a4;
        }
    }
    __syncthreads();

    const int w = t >> 6;
    const int lane = t & 63;
    if (w < 4) {
        const float4 v = *(const float4*)&att_s[w][lane * 4];
        float mx = fmaxf(fmaxf(v.x, v.y), fmaxf(v.z, v.w));
        #pragma unroll
        for (int off = 1; off < 64; off <<= 1) mx = fmaxf(mx, __shfl_xor(mx, off, 64));
        float4 e;
        e.x = __expf(v.x - mx); e.y = __expf(v.y - mx);
        e.z = __expf(v.z - mx); e.w = __expf(v.w - mx);
        float s = e.x + e.y + e.z + e.w;
        #pragma unroll
        for (int off = 1; off < 64; off <<= 1) s += __shfl_xor(s, off, 64);
        const float inv = 1.f / s;
        float4 o;
        o.x = e.x * inv; o.y = e.y * inv; o.z = e.z * inv; o.w = e.w * inv;
        *(float4*)&out[(size_t)(b * NN + n0 + w) * NN + lane * 4] = o;
    }
}

extern "C" void kernel_launch(void* const* d_in, const int* in_sizes, int n_in,
                              void* d_out, int out_size, void* d_ws, size_t ws_size,
                              hipStream_t stream) {
    const float* feat  = (const float*)d_in[0];
    const float* gfeat = (const float*)d_in[1];
    const float* adj   = (const float*)d_in[2];
    const float* Wf    = (const float*)d_in[3];
    const float* bf    = (const float*)d_in[4];
    const float* Wg    = (const float*)d_in[5];
    const float* bg    = (const float*)d_in[6];
    const float* Cf    = (const float*)d_in[7];
    const float* Cg    = (const float*)d_in[9];
    const float* a_w   = (const float*)d_in[11];
    float* out = (float*)d_out;

    float* pf   = (float*)d_ws;                    // [ROWS][HID] 512 KB
    float* pg   = pf + (size_t)ROWS * HID;         // [ROWS][HID] 512 KB
    float* scfg = pg + (size_t)ROWS * HID;         // [2*HID]

    proj_fg_kernel<<<513, 256, 0, stream>>>(feat, gfeat, Wf, bf, Wg, bg,
                                            Cf, Cg, a_w, pf, pg, scfg);
    att_kernel<<<BB * 64, 512, 0, stream>>>(pf, pg, adj, scfg, out);
}